// Round 4
// baseline (157.480 us; speedup 1.0000x reference)
//
#include <hip/hip_runtime.h>
#include <math.h>

#define NV 12
#define BATCH 4096
#define DIM 128
#define ALPHA_C 0.4f
#define BETA_C 2.0f
#define LAMDA_C 2.0f
#define LDSPAD 132   // 528B rows: 16B-aligned stride, max 2-way bank alias (free)
#define BPB 4        // batch elements per block, one wave each

__device__ __forceinline__ float dot4(const float4 a, const float4 b) {
    return a.x * b.x + a.y * b.y + a.z * b.z + a.w * b.w;
}

// 256 threads = 4 waves; each wave owns one batch element. No mid-kernel
// __syncthreads (each wave reads only LDS it wrote; lgkmcnt handles RAW);
// one barrier at the tail for the per-block atomic combine.
__global__ __launch_bounds__(256) void perb_kernel(
    const float* __restrict__ SV_A, const float* __restrict__ SV_N,
    const float* __restrict__ MV_A, const float* __restrict__ MV_N,
    float* __restrict__ out)
{
    const int wave = threadIdx.x >> 6;
    const int lane = threadIdx.x & 63;
    const int b    = blockIdx.x * BPB + wave;

    __shared__ __align__(16) float As[BPB][NV][LDSPAD];
    __shared__ __align__(16) float Ns[BPB][NV][LDSPAD];
    __shared__ __align__(16) float normsA[BPB][NV];
    __shared__ __align__(16) float normsN[BPB][NV];
    __shared__ float comm[BPB][5];

    // ---- prefetch MV rows (latency hidden under distance phase) ----
    const size_t mvoff = (size_t)b * DIM + lane;
    const float ma0 = MV_A[mvoff];
    const float ma1 = MV_A[mvoff + 64];
    const float mn0 = MV_N[mvoff];
    const float mn1 = MV_N[mvoff + 64];

    // ---- stage SV_A[:,b,:], SV_N[:,b,:]: float4, 2 rows per instruction ----
    {
        const int half = lane >> 5;            // 0: even rows, 1: odd rows
        const int c4   = (lane & 31) * 4;
        #pragma unroll
        for (int r = 0; r < NV / 2; ++r) {
            const int i = 2 * r + half;
            const size_t off = ((size_t)(i * BATCH + b)) * DIM + c4;
            *(float4*)&As[wave][i][c4] = *(const float4*)(SV_A + off);
            *(float4*)&Ns[wave][i][c4] = *(const float4*)(SV_N + off);
        }
    }

    // ---- row squared-norms, 2-way k-split: lanes 0..47 ----
    {
        float nrm = 0.f;
        if (lane < 48) {
            const int rr  = lane % 24;         // row id (0..11 A, 12..23 N)
            const int h   = lane / 24;         // k-half
            const int arr = rr >= NV;
            const int row = arr ? rr - NV : rr;
            const float* p = (arr ? &Ns[wave][row][0] : &As[wave][row][0]) + h * 64;
            #pragma unroll
            for (int k = 0; k < 64; k += 4) {
                const float4 v = *(const float4*)(p + k);
                nrm += dot4(v, v);
            }
        }
        nrm += __shfl_down(nrm, 24, 64);
        if (lane < 2 * NV) {
            const int arr = lane >= NV;
            const int row = arr ? lane - NV : lane;
            if (arr) normsN[wave][row] = nrm;
            else     normsA[wave][row] = nrm;
        }
    }

    // ---- Gram partials: 4x4 pair tile x 4-way k-split (lanes 0..35) ----
    // lane = q*9 + tile; tile = 3*ti + tj; k-range = [32q, 32q+32)
    const int tile = lane % 9;
    const int q    = lane / 9;
    const int ti   = tile / 3;
    const int tj   = tile % 3;
    float dots[4][4] = {{0.f, 0.f, 0.f, 0.f}, {0.f, 0.f, 0.f, 0.f},
                        {0.f, 0.f, 0.f, 0.f}, {0.f, 0.f, 0.f, 0.f}};
    if (lane < 36) {
        const float* Abase = &As[wave][4 * ti][0] + q * 32;
        const float* Nbase = &Ns[wave][4 * tj][0] + q * 32;
        #pragma unroll
        for (int s = 0; s < 8; ++s) {
            float4 av[4], nv[4];
            #pragma unroll
            for (int r = 0; r < 4; ++r) av[r] = *(const float4*)(Abase + r * LDSPAD + s * 4);
            #pragma unroll
            for (int c = 0; c < 4; ++c) nv[c] = *(const float4*)(Nbase + c * LDSPAD + s * 4);
            #pragma unroll
            for (int r = 0; r < 4; ++r)
                #pragma unroll
                for (int c = 0; c < 4; ++c)
                    dots[r][c] += dot4(av[r], nv[c]);
        }
    }
    // combine k-quarters: q-partners at lane offsets 18 then 9
    #pragma unroll
    for (int r = 0; r < 4; ++r)
        #pragma unroll
        for (int c = 0; c < 4; ++c) {
            float v = dots[r][c];
            v += __shfl_down(v, 18, 64);
            v += __shfl_down(v, 9, 64);
            dots[r][c] = v;
        }

    // ---- per-tile distances + local argmin (ascending flat-p order) ----
    float best_d = 3.4e38f;
    int   best_p = 1 << 20;
    if (lane < 9) {
        const float4 na4 = *(const float4*)&normsA[wave][4 * ti];
        const float4 nn4 = *(const float4*)&normsN[wave][4 * tj];
        const float na[4] = {na4.x, na4.y, na4.z, na4.w};
        const float nn[4] = {nn4.x, nn4.y, nn4.z, nn4.w};
        #pragma unroll
        for (int r = 0; r < 4; ++r)
            #pragma unroll
            for (int c = 0; c < 4; ++c) {
                const float d = na[r] + nn[c] - 2.f * dots[r][c];
                const int   p = (4 * ti + r) * NV + (4 * tj + c);
                if (d < best_d) { best_d = d; best_p = p; }   // ascending p: strict <
            }
    }
    // ---- cross-lane argmin over 9 tile-lanes (ties: smaller p wins) ----
    #pragma unroll
    for (int off = 8; off > 0; off >>= 1) {
        const float od = __shfl_down(best_d, off, 64);
        const int   op = __shfl_down(best_p, off, 64);
        if (od < best_d || (od == best_d && op < best_p)) { best_d = od; best_p = op; }
    }
    best_d = __shfl(best_d, 0, 64);
    best_p = __shfl(best_p, 0, 64);

    const int istar = best_p / NV;
    const int jstar = best_p % NV;

    // ---- three 128-dim norms with all 64 lanes (MV already in regs) ----
    float sa, sc, sm;
    {
        const float fa0 = As[wave][istar][lane];
        const float fa1 = As[wave][istar][lane + 64];
        const float fn0 = Ns[wave][jstar][lane];
        const float fn1 = Ns[wave][jstar][lane + 64];
        float d1;
        d1 = ma0 - fa0; sa  = d1 * d1;
        d1 = ma1 - fa1; sa += d1 * d1;
        d1 = mn0 - fn0; sc  = d1 * d1;
        d1 = mn1 - fn1; sc += d1 * d1;
        d1 = ma0 - mn0; sm  = d1 * d1;
        d1 = ma1 - mn1; sm += d1 * d1;
    }
    #pragma unroll
    for (int off = 32; off > 0; off >>= 1) {
        sa += __shfl_down(sa, off, 64);
        sc += __shfl_down(sc, off, 64);
        sm += __shfl_down(sm, off, 64);
    }

    if (lane == 0) {
        const float mc    = fmaxf(best_d, 0.f);
        const float a_cl  = sqrtf(sa);
        const float c_in  = sqrtf(sc);
        const float mv_in = sqrtf(sm);
        const float loss  = LAMDA_C * (fmaxf(BETA_C - mc, 0.f) + fmaxf(BETA_C - mv_in, 0.f))
                          + fmaxf(a_cl - ALPHA_C, 0.f) + fmaxf(c_in - ALPHA_C, 0.f);
        const float z = sqrtf(mc);
        comm[wave][0] = loss;
        comm[wave][1] = (loss != 0.f) ? 1.f : 0.f;
        comm[wave][2] = z;
        comm[wave][3] = 0.5f * (sqrtf(a_cl) + sqrtf(c_in));
        comm[wave][4] = z;
    }
    __syncthreads();

    // ---- per-block combine, then one atomic set per block ----
    if (threadIdx.x == 0) {
        float sl = 0.f, sn = 0.f, ss = 0.f, sh = 0.f, mn = 3.4e38f;
        #pragma unroll
        for (int w = 0; w < BPB; ++w) {
            sl += comm[w][0]; sn += comm[w][1]; ss += comm[w][2]; sh += comm[w][3];
            mn = fminf(mn, comm[w][4]);
        }
        const float inv = 1.0f / (float)BATCH;
        atomicAdd(&out[0], sl * inv);                       // avg_loss
        atomicAdd(&out[1], sn);                             // count_nonzero
        atomicAdd(&out[2], ss * inv);                       // mean sqrt(mc)
        atomicAdd(&out[3], sh * inv);                       // 0.5*(mean+mean)
        atomicMin((unsigned int*)&out[4], __float_as_uint(mn)); // min sqrt(mc), >=0
    }
}

extern "C" void kernel_launch(void* const* d_in, const int* in_sizes, int n_in,
                              void* d_out, int out_size, void* d_ws, size_t ws_size,
                              hipStream_t stream) {
    const float* SV_A = (const float*)d_in[0];
    const float* SV_N = (const float*)d_in[1];
    const float* MV_A = (const float*)d_in[2];
    const float* MV_N = (const float*)d_in[3];
    float* out = (float*)d_out;

    // init accumulators: sums <- 0.0f, min slot <- 0xFFFFFFFF (uint max)
    hipMemsetAsync(out, 0, (size_t)out_size * sizeof(float), stream);
    hipMemsetAsync((char*)out + 4 * sizeof(float), 0xFF, sizeof(float), stream);

    perb_kernel<<<BATCH / BPB, 256, 0, stream>>>(SV_A, SV_N, MV_A, MV_N, out);
}

// Round 5
// 97.650 us; speedup vs baseline: 1.6127x; 1.6127x over previous
//
#include <hip/hip_runtime.h>
#include <math.h>

#define NV 12
#define BATCH 4096
#define DIM 128
#define ALPHA_C 0.4f
#define BETA_C 2.0f
#define LAMDA_C 2.0f
#define BPB 4          // batch elements per block, one wave each
#define HPAD 136       // hi/lo row pad (shorts): 272B rows, 16B-aligned for b128
#define GPAD 26        // Gram row stride (floats): <=2-way bank alias

typedef short short8 __attribute__((ext_vector_type(8)));
typedef float f32x16 __attribute__((ext_vector_type(16)));

__device__ __forceinline__ unsigned short f2bf(float f) {   // RNE fp32->bf16
    unsigned int u = __float_as_uint(f);
    return (unsigned short)((u + 0x7fffu + ((u >> 16) & 1u)) >> 16);
}
__device__ __forceinline__ float bf2f(unsigned short s) {
    return __uint_as_float(((unsigned int)s) << 16);
}

// 256 threads = 4 waves; each wave owns one batch element. All LDS use is
// wave-local (no __syncthreads; compiler lgkmcnt handles same-wave RAW).
// Per b: G = X.X^T via 32x32x16 bf16 MFMA with hi/lo split precision,
// X = [12 A-rows; 12 N-rows] (rows 24..31 of the MFMA tile are ignored).
__global__ __launch_bounds__(256) void perb_kernel(
    const float* __restrict__ SV_A, const float* __restrict__ SV_N,
    const float* __restrict__ MV_A, const float* __restrict__ MV_N,
    float4* __restrict__ perb)
{
    const int wave = threadIdx.x >> 6;
    const int lane = threadIdx.x & 63;
    const int b    = blockIdx.x * BPB + wave;

    __shared__ __align__(16) unsigned short Hi[BPB][24][HPAD];
    __shared__ __align__(16) unsigned short Lo[BPB][24][HPAD];
    __shared__ __align__(16) float G[BPB][24][GPAD];

    // ---- prefetch MV rows ----
    const size_t mvoff = (size_t)b * DIM + lane;
    const float ma0 = MV_A[mvoff];
    const float ma1 = MV_A[mvoff + 64];
    const float mn0 = MV_N[mvoff];
    const float mn1 = MV_N[mvoff + 64];

    // ---- stage: global float4 -> bf16 hi/lo planes (2 rows per instr) ----
    {
        const int half = lane >> 5;
        const int c4   = (lane & 31) * 4;
        #pragma unroll
        for (int rr = 0; rr < NV / 2; ++rr) {
            const int i = 2 * rr + half;
            const size_t off = ((size_t)(i * BATCH + b)) * DIM + c4;
            #pragma unroll
            for (int arr = 0; arr < 2; ++arr) {
                const float4 v = *(const float4*)((arr ? SV_N : SV_A) + off);
                const unsigned short h0 = f2bf(v.x), h1 = f2bf(v.y);
                const unsigned short h2 = f2bf(v.z), h3 = f2bf(v.w);
                const unsigned short l0 = f2bf(v.x - bf2f(h0));
                const unsigned short l1 = f2bf(v.y - bf2f(h1));
                const unsigned short l2 = f2bf(v.z - bf2f(h2));
                const unsigned short l3 = f2bf(v.w - bf2f(h3));
                const int row = arr * NV + i;
                uint2 hw, lw;
                hw.x = (unsigned int)h0 | ((unsigned int)h1 << 16);
                hw.y = (unsigned int)h2 | ((unsigned int)h3 << 16);
                lw.x = (unsigned int)l0 | ((unsigned int)l1 << 16);
                lw.y = (unsigned int)l2 | ((unsigned int)l3 << 16);
                *(uint2*)&Hi[wave][row][c4] = hw;
                *(uint2*)&Lo[wave][row][c4] = lw;
            }
        }
    }

    // ---- Gram via MFMA: A-frag == B-frag for X.X^T ----
    // frag layout 32x32x16: elem j of lane = X[lane&31][(lane>>5)*8 + j + 16*kb]
    {
        int r = lane & 31;
        if (r >= 24) r = 0;                    // pad rows: duplicate row 0, ignored
        const int h = lane >> 5;
        const unsigned short* hbase = &Hi[wave][r][h * 8];
        const unsigned short* lbase = &Lo[wave][r][h * 8];
        f32x16 acc = {0.f, 0.f, 0.f, 0.f, 0.f, 0.f, 0.f, 0.f,
                      0.f, 0.f, 0.f, 0.f, 0.f, 0.f, 0.f, 0.f};
        #pragma unroll
        for (int kb = 0; kb < 8; ++kb) {
            const short8 hv = *(const short8*)(hbase + kb * 16);
            const short8 lv = *(const short8*)(lbase + kb * 16);
            acc = __builtin_amdgcn_mfma_f32_32x32x16_bf16(hv, hv, acc, 0, 0, 0);
            acc = __builtin_amdgcn_mfma_f32_32x32x16_bf16(hv, lv, acc, 0, 0, 0);
            acc = __builtin_amdgcn_mfma_f32_32x32x16_bf16(lv, hv, acc, 0, 0, 0);
        }
        // C/D: col = lane&31, row = (reg&3) + 8*(reg>>2) + 4*(lane>>5)
        const int col = lane & 31;
        if (col < 24) {
            #pragma unroll
            for (int rg = 0; rg < 12; ++rg) {   // rg>=12 -> rows>=24, skip
                const int row = (rg & 3) + 8 * (rg >> 2) + 4 * h;
                G[wave][row][col] = acc[rg];
            }
        }
    }

    // ---- distances from G: 2x2 pair tile, lanes 0..35 ----
    float best_d = 3.4e38f;
    int   best_p = 1 << 20;
    if (lane < 36) {
        const int i2 = lane / 6;
        const int j2 = lane % 6;
        const int ia0 = 2 * i2, ia1 = 2 * i2 + 1;
        const int jn0 = 12 + 2 * j2, jn1 = jn0 + 1;
        const float2 g0 = *(const float2*)&G[wave][ia0][jn0];
        const float2 g1 = *(const float2*)&G[wave][ia1][jn0];
        const float na0 = G[wave][ia0][ia0];
        const float na1 = G[wave][ia1][ia1];
        const float nn0 = G[wave][jn0][jn0];
        const float nn1 = G[wave][jn1][jn1];
        const float d00 = na0 + nn0 - 2.f * g0.x;
        const float d01 = na0 + nn1 - 2.f * g0.y;
        const float d10 = na1 + nn0 - 2.f * g1.x;
        const float d11 = na1 + nn1 - 2.f * g1.y;
        const int p00 = ia0 * NV + 2 * j2;     // ascending flat-p: strict <
        best_d = d00; best_p = p00;
        if (d01 < best_d) { best_d = d01; best_p = p00 + 1; }
        if (d10 < best_d) { best_d = d10; best_p = p00 + NV; }
        if (d11 < best_d) { best_d = d11; best_p = p00 + NV + 1; }
    }
    #pragma unroll
    for (int off = 32; off > 0; off >>= 1) {
        const float od = __shfl_down(best_d, off, 64);
        const int   op = __shfl_down(best_p, off, 64);
        if (od < best_d || (od == best_d && op < best_p)) { best_d = od; best_p = op; }
    }
    best_d = __shfl(best_d, 0, 64);
    best_p = __shfl(best_p, 0, 64);

    const int istar = best_p / NV;
    const int jstar = best_p % NV;

    // ---- exact fp32 cluster norms: winning rows re-read from global (L2-hot,
    //      coalesced: 128 consecutive floats per wave) ----
    float sa, sc, sm;
    {
        const size_t offA = ((size_t)(istar * BATCH + b)) * DIM + lane;
        const size_t offN = ((size_t)(jstar * BATCH + b)) * DIM + lane;
        const float fa0 = SV_A[offA];
        const float fa1 = SV_A[offA + 64];
        const float fn0 = SV_N[offN];
        const float fn1 = SV_N[offN + 64];
        float d1;
        d1 = ma0 - fa0; sa  = d1 * d1;
        d1 = ma1 - fa1; sa += d1 * d1;
        d1 = mn0 - fn0; sc  = d1 * d1;
        d1 = mn1 - fn1; sc += d1 * d1;
        d1 = ma0 - mn0; sm  = d1 * d1;
        d1 = ma1 - mn1; sm += d1 * d1;
    }
    #pragma unroll
    for (int off = 32; off > 0; off >>= 1) {
        sa += __shfl_down(sa, off, 64);
        sc += __shfl_down(sc, off, 64);
        sm += __shfl_down(sm, off, 64);
    }

    if (lane == 0) {
        const float mc    = fmaxf(best_d, 0.f);
        const float a_cl  = sqrtf(sa);
        const float c_in  = sqrtf(sc);
        const float mv_in = sqrtf(sm);
        const float loss  = LAMDA_C * (fmaxf(BETA_C - mc, 0.f) + fmaxf(BETA_C - mv_in, 0.f))
                          + fmaxf(a_cl - ALPHA_C, 0.f) + fmaxf(c_in - ALPHA_C, 0.f);
        float4 o;
        o.x = loss;
        o.y = (loss != 0.f) ? 1.f : 0.f;
        o.z = sqrtf(mc);
        o.w = 0.5f * (sqrtf(a_cl) + sqrtf(c_in));
        perb[b] = o;
    }
}

// Single-block deterministic final reduction: 1024 threads, 4 records each.
__global__ __launch_bounds__(1024) void final_kernel(
    const float4* __restrict__ perb, float* __restrict__ out)
{
    const int t = threadIdx.x;
    float sl = 0.f, sn = 0.f, ss = 0.f, sh = 0.f, mnv = 3.4e38f;
    #pragma unroll
    for (int u = 0; u < BATCH / 1024; ++u) {
        const float4 v = perb[t + u * 1024];
        sl += v.x; sn += v.y; ss += v.z; sh += v.w;
        mnv = fminf(mnv, v.z);
    }
    #pragma unroll
    for (int off = 32; off > 0; off >>= 1) {
        sl += __shfl_down(sl, off, 64);
        sn += __shfl_down(sn, off, 64);
        ss += __shfl_down(ss, off, 64);
        sh += __shfl_down(sh, off, 64);
        mnv = fminf(mnv, __shfl_down(mnv, off, 64));
    }
    __shared__ float r[16][5];
    const int w = t >> 6;
    if ((t & 63) == 0) {
        r[w][0] = sl; r[w][1] = sn; r[w][2] = ss; r[w][3] = sh; r[w][4] = mnv;
    }
    __syncthreads();
    if (t == 0) {
        #pragma unroll
        for (int i = 1; i < 16; ++i) {
            sl += r[i][0]; sn += r[i][1]; ss += r[i][2]; sh += r[i][3];
            mnv = fminf(mnv, r[i][4]);
        }
        const float inv = 1.0f / (float)BATCH;
        out[0] = sl * inv;   // avg_loss
        out[1] = sn;         // count_nonzero
        out[2] = ss * inv;   // mean(sqrt(mc_inter))
        out[3] = sh * inv;   // 0.5*(mean sqrt(a_clstr) + mean sqrt(c_intra))
        out[4] = mnv;        // min(sqrt(mc_inter))
    }
}

extern "C" void kernel_launch(void* const* d_in, const int* in_sizes, int n_in,
                              void* d_out, int out_size, void* d_ws, size_t ws_size,
                              hipStream_t stream) {
    const float* SV_A = (const float*)d_in[0];
    const float* SV_N = (const float*)d_in[1];
    const float* MV_A = (const float*)d_in[2];
    const float* MV_N = (const float*)d_in[3];
    float* out = (float*)d_out;
    float4* perb = (float4*)d_ws;   // 4096 * 16B = 64 KiB

    perb_kernel<<<BATCH / BPB, 256, 0, stream>>>(SV_A, SV_N, MV_A, MV_N, perb);
    final_kernel<<<1, 1024, 0, stream>>>(perb, out);
}